// Round 4
// baseline (255.317 us; speedup 1.0000x reference)
//
#include <hip/hip_runtime.h>
#include <cstdint>

// Round 4: butterfly -> merged block-diagonal matrices -> MFMA f16 GEMM pipeline.
// Kernel 1 (build_mats): applies butterfly stages to identity columns -> merged
//   matrices in d_ws (f16): MA1[s][g][i][k] (L1 stages 0-4, blocks of 32 consecutive
//   positions), MB1[s][low][i][j] (L1 stages 5-9, stride-32 blocks), M2A[b2][i][k]
//   (L2 stages 0-4), M2B[low2][i<32][j:64] (L2 stages 5-10, only out<1024 rows).
// Kernel 2 (glu_fused): per block 16 rows, 1024 thr (16 waves), LDS 153 KiB:
//   X(f16) -> per stack: groupA (32x 32x32 GEMM) -> Yg -> groupB -> (+b1, GLU via
//   A-halves in regs) -> U -> L2A (64x 32x32) -> V (overlaid on U, wave-private
//   stripes) -> L2B (32x 32x64) -> +b2 -> out.
// All LDS B-frag reads are ds_read_b128 with 16-B XOR swizzle ^((r&3)<<4) and
// row strides padded to 4 mod 32 dwords; C-frags pack across each wave's owned
// batch quartet/octet into b64/b128 writes.

typedef _Float16 f16;
typedef f16  f16x8 __attribute__((ext_vector_type(8)));
typedef f16  f16x4 __attribute__((ext_vector_type(4)));
typedef float f32x4 __attribute__((ext_vector_type(4)));

#define OFF_MA1 0
#define OFF_MB1 131072
#define OFF_M2A 262144
#define OFF_M2B 327680

// LDS byte offsets (strides padded so row-coef == 4 mod 32 dwords -> 2-way max)
#define XS   2064        // X row stride bytes: (1024+8) f16
#define YGS  2576        // Yg row stride bytes: 32*40 f16 + 16B pad
#define US   5136        // U  row stride bytes: 64*40 f16 + 16B pad
#define LDS_X   0
#define LDS_YG  33024    // 16*2064
#define LDS_U   74240    // + 16*2576
#define LDS_TOT 156416   // + 16*5136

// ---------------------------------------------------------------- precompute
template<int NPOS, int J0, int NSTG, int STEPI>
__device__ __forceinline__ void build_cols(const float4* twq, int halfn, int pbase,
                                           int c, float* v) {
    #pragma unroll
    for (int i = 0; i < NPOS; ++i) v[i] = (i == c) ? 1.f : 0.f;
    #pragma unroll
    for (int jj = 0; jj < NSTG; ++jj) {
        const int j   = J0 + jj;
        const int sig = 1 << j;
        const int dl  = sig / STEPI;   // local pair distance (compile-time)
        #pragma unroll
        for (int m = 0; m < NPOS/2; ++m) {
            const int i0 = (m/dl)*(2*dl) + (m % dl);
            const int i1 = i0 + dl;
            const int p0 = pbase + i0*STEPI;
            const int tidx = ((p0 >> (j+1)) << j) | (p0 & (sig-1));
            const float4 t = twq[j*halfn + tidx];
            const float a = v[i0], b = v[i1];
            v[i0] = t.x*a + t.y*b;
            v[i1] = t.z*a + t.w*b;
        }
    }
}

__global__ void build_mats(const float* __restrict__ tw1,
                           const float* __restrict__ tw2,
                           f16* __restrict__ mats) {
    const int u = blockIdx.x;
    const int c = threadIdx.x;
    const float4* tw1q = (const float4*)tw1;   // (4,10,512,2,2)
    const float4* tw2q = (const float4*)tw2;   // (1,11,1024,2,2)
    float v[64];
    if (u < 128) {                 // MA1: s = u>>5, g = u&31
        if (c >= 32) return;
        const int s = u >> 5, g = u & 31;
        build_cols<32, 0, 5, 1>(tw1q + s*10*512, 512, 32*g, c, v);
        f16* dst = mats + OFF_MA1 + ((s*32 + g)*32)*32 + c;
        #pragma unroll
        for (int i = 0; i < 32; ++i) dst[i*32] = (f16)v[i];
    } else if (u < 256) {          // MB1: s, low
        if (c >= 32) return;
        const int s = (u - 128) >> 5, low = u & 31;
        build_cols<32, 5, 5, 32>(tw1q + s*10*512, 512, low, c, v);
        f16* dst = mats + OFF_MB1 + ((s*32 + low)*32)*32 + c;
        #pragma unroll
        for (int i = 0; i < 32; ++i) dst[i*32] = (f16)v[i];
    } else if (u < 320) {          // M2A: b2
        if (c >= 32) return;
        const int b2 = u - 256;
        build_cols<32, 0, 5, 1>(tw2q, 1024, 32*b2, c, v);
        f16* dst = mats + OFF_M2A + (b2*32)*32 + c;
        #pragma unroll
        for (int i = 0; i < 32; ++i) dst[i*32] = (f16)v[i];
    } else {                       // M2B: low2, c in [0,64)
        const int low2 = u - 320;
        build_cols<64, 5, 6, 32>(tw2q, 1024, low2, c, v);
        f16* dst = mats + OFF_M2B + (low2*32)*64 + c;
        #pragma unroll
        for (int i = 0; i < 32; ++i) dst[i*64] = (f16)v[i];   // keep only out<1024 rows
    }
}

// ---------------------------------------------------------------- main kernel
__device__ __forceinline__ float sigm(float z) {
    return __builtin_amdgcn_rcpf(1.f + __expf(-z));
}

__global__ __launch_bounds__(1024, 4) void glu_fused(
    const float* __restrict__ x, const float* __restrict__ b1,
    const float* __restrict__ b2, const f16* __restrict__ mats,
    float* __restrict__ out)
{
    extern __shared__ char sm[];
    const int t     = threadIdx.x;
    const int w     = t >> 6;          // wave 0..15
    const int l     = t & 63;
    const int r     = l & 15;          // data-row lane (n-dim)
    const int quad  = l >> 4;          // 0..3
    const int quart = w & 7;           // batch quartet / octet id
    const int itile = w >> 3;          // 0..1 (m'-tile)
    const long row0 = (long)blockIdx.x * 16;
    const int rsw   = (r & 3);         // swizzle seed

    // ---- X load: wave w -> row w, f32 -> f16 ----
    {
        const float4* xp = (const float4*)(x + (row0 + w)*1024 + l*16);
        const float4 a0 = xp[0], a1 = xp[1], a2 = xp[2], a3 = xp[3];
        f16x8 o0, o1;
        o0[0]=(f16)a0.x; o0[1]=(f16)a0.y; o0[2]=(f16)a0.z; o0[3]=(f16)a0.w;
        o0[4]=(f16)a1.x; o0[5]=(f16)a1.y; o0[6]=(f16)a1.z; o0[7]=(f16)a1.w;
        o1[0]=(f16)a2.x; o1[1]=(f16)a2.y; o1[2]=(f16)a2.z; o1[3]=(f16)a2.w;
        o1[4]=(f16)a3.x; o1[5]=(f16)a3.y; o1[6]=(f16)a3.z; o1[7]=(f16)a3.w;
        char* xd = sm + LDS_X + w*XS + l*32;
        *(f16x8*)xd = o0;
        *(f16x8*)(xd + 16) = o1;
    }
    __syncthreads();

    float aR[2][4][4];   // GLU a-halves: [s][li][reg]

    #pragma unroll
    for (int s = 0; s < 4; ++s) {
        // ---- groupA: h5 = MA1 * x  (batches g, wave owns quartet) ----
        f32x4 accA[4];
        #pragma unroll
        for (int gi = 0; gi < 4; ++gi) {
            const int g = quart*4 + gi;
            const f16x8 bf = *(const f16x8*)(sm + LDS_X + r*XS + (32*g + quad*8)*2);
            const f16x8 af = *(const f16x8*)(mats + OFF_MA1 +
                                 ((s*32 + g)*32 + itile*16 + r)*32 + quad*8);
            f32x4 z = {0.f, 0.f, 0.f, 0.f};
            accA[gi] = __builtin_amdgcn_mfma_f32_16x16x32_f16(af, bf, z, 0, 0, 0);
        }
        __syncthreads();   // prior-stack groupB reads of Yg complete
        #pragma unroll
        for (int reg = 0; reg < 4; ++reg) {
            const int i = itile*16 + quad*4 + reg;
            f16x4 pk;
            pk[0]=(f16)accA[0][reg]; pk[1]=(f16)accA[1][reg];
            pk[2]=(f16)accA[2][reg]; pk[3]=(f16)accA[3][reg];
            *(f16x4*)(sm + LDS_YG + r*YGS + i*80 +
                      ((((quart>>1) ^ rsw) << 4) | ((quart & 1) << 3))) = pk;
        }
        __syncthreads();   // Yg ready
        // ---- groupB: h = MB1 * h5  (batches low, wave owns quartet) ----
        f32x4 accB[4];
        #pragma unroll
        for (int li = 0; li < 4; ++li) {
            const int low = quart*4 + li;
            const f16x8 bf = *(const f16x8*)(sm + LDS_YG + r*YGS + low*80 +
                                             ((quad ^ rsw) << 4));
            const f16x8 af = *(const f16x8*)(mats + OFF_MB1 +
                                 ((s*32 + low)*32 + itile*16 + r)*32 + quad*8);
            f32x4 z = {0.f, 0.f, 0.f, 0.f};
            accB[li] = __builtin_amdgcn_mfma_f32_16x16x32_f16(af, bf, z, 0, 0, 0);
        }
        if (s < 2) {       // a-half: keep (+bias) in regs
            #pragma unroll
            for (int reg = 0; reg < 4; ++reg) {
                const int i = itile*16 + quad*4 + reg;
                const float4 bv = *(const float4*)(b1 + s*1024 + 32*i + quart*4);
                aR[s][0][reg] = accB[0][reg] + bv.x;
                aR[s][1][reg] = accB[1][reg] + bv.y;
                aR[s][2][reg] = accB[2][reg] + bv.z;
                aR[s][3][reg] = accB[3][reg] + bv.w;
            }
        } else {           // gate-half: GLU -> U
            #pragma unroll
            for (int reg = 0; reg < 4; ++reg) {
                const int i = itile*16 + quad*4 + reg;
                const float4 bv = *(const float4*)(b1 + s*1024 + 32*i + quart*4);
                f16x4 pk;
                pk[0] = (f16)(aR[s-2][0][reg] * sigm(accB[0][reg] + bv.x));
                pk[1] = (f16)(aR[s-2][1][reg] * sigm(accB[1][reg] + bv.y));
                pk[2] = (f16)(aR[s-2][2][reg] * sigm(accB[2][reg] + bv.z));
                pk[3] = (f16)(aR[s-2][3][reg] * sigm(accB[3][reg] + bv.w));
                *(f16x4*)(sm + LDS_U + r*US + ((s-2)*32 + i)*80 +
                          ((((quart>>1) ^ rsw) << 4) | ((quart & 1) << 3))) = pk;
            }
        }
    }
    __syncthreads();       // U complete

    // ---- L2A: v = M2A * u  (batches b2, wave owns octet; 2 waves/octet share reads)
    f16x8 ub[8];
    #pragma unroll
    for (int bi = 0; bi < 8; ++bi) {
        const int b2 = quart*8 + bi;
        ub[bi] = *(const f16x8*)(sm + LDS_U + r*US + b2*80 + ((quad ^ rsw) << 4));
    }
    __syncthreads();       // all U reads done before V overlays U
    f32x4 accV[8];
    #pragma unroll
    for (int bi = 0; bi < 8; ++bi) {
        const int b2 = quart*8 + bi;
        const f16x8 af = *(const f16x8*)(mats + OFF_M2A +
                             (b2*32 + itile*16 + r)*32 + quad*8);
        f32x4 z = {0.f, 0.f, 0.f, 0.f};
        accV[bi] = __builtin_amdgcn_mfma_f32_16x16x32_f16(af, ub[bi], z, 0, 0, 0);
    }
    // V[r][i2][j2] overlaid into U stripe: b2' = oct*8 + itile*4 + quad, chunk = reg
    #pragma unroll
    for (int reg = 0; reg < 4; ++reg) {
        f16x8 pk;
        pk[0]=(f16)accV[0][reg]; pk[1]=(f16)accV[1][reg];
        pk[2]=(f16)accV[2][reg]; pk[3]=(f16)accV[3][reg];
        pk[4]=(f16)accV[4][reg]; pk[5]=(f16)accV[5][reg];
        pk[6]=(f16)accV[6][reg]; pk[7]=(f16)accV[7][reg];
        *(f16x8*)(sm + LDS_U + r*US + (quart*8 + itile*4 + quad)*80 +
                  (((reg ^ rsw) << 4))) = pk;
    }
    __syncthreads();       // V ready

    // ---- L2B: out = M2B * v  (batches low2, wave owns quartet; K=64) ----
    f32x4 accO[4];
    #pragma unroll
    for (int li = 0; li < 4; ++li) {
        const int low2 = quart*4 + li;
        f32x4 z = {0.f, 0.f, 0.f, 0.f};
        #pragma unroll
        for (int h = 0; h < 2; ++h) {
            const f16x8 bf = *(const f16x8*)(sm + LDS_U + r*US +
                                 (((quad + 4*h)*8 + (low2 >> 2))*80) +
                                 ((((low2 & 3) ^ rsw) << 4)));
            const f16x8 af = *(const f16x8*)(mats + OFF_M2B +
                                 (low2*32 + itile*16 + r)*64 + h*32 + quad*8);
            z = __builtin_amdgcn_mfma_f32_16x16x32_f16(af, bf, z, 0, 0, 0);
        }
        accO[li] = z;
    }
    #pragma unroll
    for (int reg = 0; reg < 4; ++reg) {
        const int i2 = itile*16 + quad*4 + reg;
        const float4 bv = *(const float4*)(b2 + 32*i2 + quart*4);
        float4 st;
        st.x = accO[0][reg] + bv.x;
        st.y = accO[1][reg] + bv.y;
        st.z = accO[2][reg] + bv.z;
        st.w = accO[3][reg] + bv.w;
        *(float4*)(out + (row0 + r)*1024 + 32*i2 + quart*4) = st;
    }
}

extern "C" void kernel_launch(void* const* d_in, const int* in_sizes, int n_in,
                              void* d_out, int out_size, void* d_ws, size_t ws_size,
                              hipStream_t stream) {
    const float* x   = (const float*)d_in[0];
    const float* tw1 = (const float*)d_in[1];
    const float* b1  = (const float*)d_in[2];
    const float* tw2 = (const float*)d_in[3];
    const float* b2  = (const float*)d_in[4];
    float* outp = (float*)d_out;
    f16* mats = (f16*)d_ws;   // needs 917504 B

    (void)hipFuncSetAttribute((const void*)glu_fused,
                              hipFuncAttributeMaxDynamicSharedMemorySize, LDS_TOT);
    build_mats<<<352, 64, 0, stream>>>(tw1, tw2, mats);
    glu_fused<<<1024, 1024, LDS_TOT, stream>>>(x, b1, b2, mats, outp);
}